// Round 4
// baseline (258.504 us; speedup 1.0000x reference)
//
#include <hip/hip_runtime.h>
#include <math.h>

typedef __attribute__((ext_vector_type(8))) short bf16x8;
typedef __attribute__((ext_vector_type(4))) float f32x4;

#define BATCH 32
#define LL    4096
#define FDIM  128
#define NLEV  12
#define EPSF  1e-5f
#define RSQRTF 0.08838834764831845f
#define NCH   16

// ws layout (float offsets)
#define OFF_CQ 0          // 4096
#define OFF_CK 4096       // 4096
#define OFF_D  8192       // 2 (dq, dk)
#define OFF_SX 8320       // 32*128 (zeroed)
#define OFF_QS 12416      // 32*128 (zeroed)
#define OFF_KS 16512      // 32*128 (zeroed)
#define OFF_DV 20608      // 32*128
#define OFF_GP 24704      // 16*32*16384 fp32 partials = 8388608
#define OFF_GB 8413312    // G bf16: 32*16384 ushort = 262144 float slots
#define OFF_CT 8675456    // Ct bf16: 262144 float slots (end 8937600 fl = 35.8 MB)

typedef union { bf16x8 v; unsigned short u[8]; } frag_t;

__device__ inline unsigned short bfr(float f) {   // fp32 -> bf16 RTNE
    union { float f; unsigned u; } v; v.f = f;
    unsigned r = v.u + 0x7FFF + ((v.u >> 16) & 1);
    return (unsigned short)(r >> 16);
}
__device__ inline float bf2f(unsigned short h) {
    union { unsigned u; float f; } v; v.u = ((unsigned)h) << 16; return v.f;
}

// ---------------------------------------------------------------- coeff
__global__ void coeff_kernel(const float* __restrict__ qw, const float* __restrict__ qb,
                             const float* __restrict__ kw, const float* __restrict__ kb,
                             float* __restrict__ ws) {
    int l = blockIdx.x * 256 + threadIdx.x;
    float cq = 1.f, ck = 1.f;
#pragma unroll
    for (int i = 0; i < NLEV; i++) {
        int bit = (l >> i) & 1;
        cq *= qw[2 * i + bit];
        ck *= kw[2 * i + bit];
    }
    ws[OFF_CQ + l] = cq;
    ws[OFF_CK + l] = ck;
    if (l == 0) {
        float dq = 0.f, dk = 0.f;
        for (int i = 0; i < NLEV; i++) {
            dq = (qw[2 * i] + qw[2 * i + 1]) * dq + qb[i];
            dk = (kw[2 * i] + kw[2 * i + 1]) * dk + kb[i];
        }
        ws[OFF_D]     = dq;
        ws[OFF_D + 1] = dk;
    }
}

// ---------------------------------------------------------------- K1: G partials + fp32 sums
// grid (16, 32), 256 thr (2 blocks/CU). 256 rows/chunk, 4 dbuf tiles of 64 rows.
// LDS: transposed X, XOR-swizzled pitch 64 -> conflict-free ds_read_b128 frags.
__global__ __launch_bounds__(256, 2) void k1_gram(const float* __restrict__ x,
                                                  float* __restrict__ ws) {
    __shared__ __align__(16) unsigned short XsT[2][128][64];
    __shared__ float sa[128], qa[128], ka[128];
    const int b = blockIdx.y, ch = blockIdx.x;
    const int tid = threadIdx.x;
    const int wv = tid >> 6, l15 = tid & 15, quad = (tid >> 4) & 3;
    const float* Xb  = x + ((size_t)b * LL + ch * 256) * FDIM;
    const float* cqp = ws + OFF_CQ + ch * 256;
    const float* ckp = ws + OFF_CK + ch * 256;
    if (tid < 128) { sa[tid] = 0.f; qa[tid] = 0.f; ka[tid] = 0.f; }

    const int fcol = tid & 31;          // f = fcol + 32*jj
    const int r0   = (tid >> 5) * 8;    // rows r0..r0+7 within tile
    const int grpX = r0 >> 3;           // swizzle group of this thread's rows

    float sxr[4] = {0,0,0,0}, qr[4] = {0,0,0,0}, kr[4] = {0,0,0,0};
    f32x4 acc[2][8];
#pragma unroll
    for (int r_ = 0; r_ < 2; r_++)
#pragma unroll
        for (int c = 0; c < 8; c++) acc[r_][c] = (f32x4){0.f, 0.f, 0.f, 0.f};

    // ---- load + store tile 0
    {
        float vb[4][8], cqb[8], ckb[8];
#pragma unroll
        for (int i = 0; i < 8; i++) { cqb[i] = cqp[r0 + i]; ckb[i] = ckp[r0 + i]; }
#pragma unroll
        for (int jj = 0; jj < 4; jj++) {
            int f = fcol + 32 * jj;
#pragma unroll
            for (int i = 0; i < 8; i++) vb[jj][i] = Xb[(size_t)(r0 + i) * FDIM + f];
        }
#pragma unroll
        for (int jj = 0; jj < 4; jj++) {
            int f = fcol + 32 * jj;
            unsigned short h[8];
#pragma unroll
            for (int i = 0; i < 8; i++) {
                float v = vb[jj][i];
                sxr[jj] += v; qr[jj] += cqb[i] * v; kr[jj] += ckb[i] * v;
                h[i] = bfr(v);
            }
            unsigned short* dst = &XsT[0][f][(grpX ^ (f & 7)) * 8];
            ushort4 h0 = {h[0], h[1], h[2], h[3]}, h1 = {h[4], h[5], h[6], h[7]};
            *(ushort4*)dst = h0; *(ushort4*)(dst + 4) = h1;
        }
    }
    __syncthreads();

    for (int t = 0; t < 4; t++) {
        float nvb[4][8], ncq[8], nck[8];
        if (t < 3) {                               // prefetch tile t+1
            const float* Xt = Xb + (size_t)((t + 1) * 64) * FDIM;
#pragma unroll
            for (int i = 0; i < 8; i++) {
                ncq[i] = cqp[(t + 1) * 64 + r0 + i];
                nck[i] = ckp[(t + 1) * 64 + r0 + i];
            }
#pragma unroll
            for (int jj = 0; jj < 4; jj++) {
                int f = fcol + 32 * jj;
#pragma unroll
                for (int i = 0; i < 8; i++) nvb[jj][i] = Xt[(size_t)(r0 + i) * FDIM + f];
            }
        }
        // compute on buf t&1
#pragma unroll
        for (int kk = 0; kk < 2; kk++) {
            bf16x8 fr[8];
#pragma unroll
            for (int t2 = 0; t2 < 8; t2++) {
                int f = t2 * 16 + l15;
                fr[t2] = *(const bf16x8*)&XsT[t & 1][f][((kk * 4 + quad) ^ (f & 7)) * 8];
            }
#pragma unroll
            for (int r_ = 0; r_ < 2; r_++)
#pragma unroll
                for (int c = 0; c < 8; c++)
                    acc[r_][c] = __builtin_amdgcn_mfma_f32_16x16x32_bf16(
                        fr[2 * wv + r_], fr[c], acc[r_][c], 0, 0, 0);
        }
        if (t < 3) {                               // cvt + store into buf (t+1)&1
#pragma unroll
            for (int jj = 0; jj < 4; jj++) {
                int f = fcol + 32 * jj;
                unsigned short h[8];
#pragma unroll
                for (int i = 0; i < 8; i++) {
                    float v = nvb[jj][i];
                    sxr[jj] += v; qr[jj] += ncq[i] * v; kr[jj] += nck[i] * v;
                    h[i] = bfr(v);
                }
                unsigned short* dst = &XsT[(t + 1) & 1][f][(grpX ^ (f & 7)) * 8];
                ushort4 h0 = {h[0], h[1], h[2], h[3]}, h1 = {h[4], h[5], h[6], h[7]};
                *(ushort4*)dst = h0; *(ushort4*)(dst + 4) = h1;
            }
        }
        __syncthreads();
    }

    float* Gp = ws + OFF_GP + (((size_t)ch * 32 + b) << 14);
#pragma unroll
    for (int r_ = 0; r_ < 2; r_++)
#pragma unroll
        for (int c = 0; c < 8; c++)
#pragma unroll
            for (int reg = 0; reg < 4; reg++)
                Gp[(((2 * wv + r_) * 16 + quad * 4 + reg) << 7) + c * 16 + l15] =
                    acc[r_][c][reg];
#pragma unroll
    for (int jj = 0; jj < 4; jj++) {
        int f = fcol + 32 * jj;
        atomicAdd(&sa[f], sxr[jj]);
        atomicAdd(&qa[f], qr[jj]);
        atomicAdd(&ka[f], kr[jj]);
    }
    __syncthreads();
    if (tid < 128) {
        atomicAdd(&ws[OFF_SX + b * FDIM + tid], sa[tid]);
        atomicAdd(&ws[OFF_QS + b * FDIM + tid], qa[tid]);
        atomicAdd(&ws[OFF_KS + b * FDIM + tid], ka[tid]);
    }
}

// ---------------------------------------------------------------- Kred: sum 16 partials -> G bf16
__global__ void kred(float* __restrict__ ws) {
    const int b = blockIdx.x >> 2, s = blockIdx.x & 3;
    const int tid = threadIdx.x;
    const int base = s << 12;
    float acc[16];
#pragma unroll
    for (int i = 0; i < 16; i++) acc[i] = 0.f;
    for (int ch = 0; ch < NCH; ch++) {
        const float* gp = ws + OFF_GP + (((size_t)ch * 32 + b) << 14) + base;
#pragma unroll
        for (int i = 0; i < 4; i++) {
            float4 v = *(const float4*)&gp[(tid + i * 256) * 4];
            acc[i * 4 + 0] += v.x; acc[i * 4 + 1] += v.y;
            acc[i * 4 + 2] += v.z; acc[i * 4 + 3] += v.w;
        }
    }
    unsigned short* gb = (unsigned short*)(ws + OFF_GB) + ((size_t)b << 14) + base;
#pragma unroll
    for (int i = 0; i < 4; i++) {
        ushort4 h;
        h.x = bfr(acc[i * 4 + 0]); h.y = bfr(acc[i * 4 + 1]);
        h.z = bfr(acc[i * 4 + 2]); h.w = bfr(acc[i * 4 + 3]);
        *(ushort4*)&gb[(tid + i * 256) * 4] = h;
    }
}

// ---------------------------------------------------------------- K3: per-batch 128^3 chain
// grid 32, 256 thr. P (softmax+I) precomputed once into LDS (P row-major + Pt transposed).
__global__ __launch_bounds__(256) void k3_chain(float* __restrict__ ws,
                                                const float* __restrict__ ffw,
                                                const float* __restrict__ gamma,
                                                const float* __restrict__ beta) {
    __shared__ __align__(16) unsigned short P[128][136];
    __shared__ __align__(16) unsigned short Pt[128][136];
    __shared__ __align__(16) unsigned short Rt[128][136];
    __shared__ float qs[128], kvv[128], mv[128], invs[128], sxv[128],
                     a1v[128], a2v[128], w0v[128], vacc[128], kmm[2];
    const int b = blockIdx.x, tid = threadIdx.x;
    const int wv = tid >> 6, l15 = tid & 15, quad = (tid >> 4) & 3;
    const unsigned short* Gb = (const unsigned short*)(ws + OFF_GB) + ((size_t)b << 14);

    if (tid < 128) {
        sxv[tid] = ws[OFF_SX + b * FDIM + tid];
        qs[tid]  = (ws[OFF_QS + b * FDIM + tid] + ws[OFF_D]) * RSQRTF;
        kvv[tid] = ws[OFF_KS + b * FDIM + tid] + ws[OFF_D + 1];
        vacc[tid] = 0.f;
    }
    __syncthreads();
    if (tid < 64) {
        float a = kvv[tid], c = kvv[tid + 64];
        float mx = fmaxf(a, c), mn = fminf(a, c);
        for (int o = 32; o; o >>= 1) {
            mx = fmaxf(mx, __shfl_xor(mx, o));
            mn = fminf(mn, __shfl_xor(mn, o));
        }
        if (tid == 0) { kmm[0] = mn; kmm[1] = mx; }
    }
    __syncthreads();
    if (tid < 128) {
        float qf = qs[tid];
        float m  = fmaxf(qf * kmm[0], qf * kmm[1]);
        float s  = 0.f;
        for (int g = 0; g < 128; g++) s += __expf(qf * kvv[g] - m);
        mv[tid] = m; invs[tid] = 1.f / s;
    }
    __syncthreads();
    {   // P-gen: P'[f][g] = softmax + I
        int f = tid & 127, gh = tid >> 7;
        float qf = qs[f], iv = invs[f], m = mv[f];
        for (int g2 = 0; g2 < 64; g2++) {
            int g = gh * 64 + g2;
            float e = __expf(qf * kvv[g] - m) * iv + (f == g ? 1.f : 0.f);
            unsigned short h = bfr(e);
            P[f][g] = h; Pt[g][f] = h;
        }
    }
    __syncthreads();
    if (tid < 128) {                   // w0 = sX @ P'
        float w = 0.f;
        for (int f = 0; f < 128; f++) w += sxv[f] * bf2f(Pt[tid][f]);
        w0v[tid] = w;
    }
    __syncthreads();
    // ---- m1: T0t = P'^T G ; diag(T0 P') -> vacc
    {
        f32x4 acc[2][8];
#pragma unroll
        for (int r_ = 0; r_ < 2; r_++)
#pragma unroll
            for (int c = 0; c < 8; c++) acc[r_][c] = (f32x4){0.f, 0.f, 0.f, 0.f};
#pragma unroll
        for (int kk = 0; kk < 4; kk++) {
            const int kb = kk * 32 + quad * 8;
            bf16x8 af[2];
#pragma unroll
            for (int r_ = 0; r_ < 2; r_++)
                af[r_] = *(const bf16x8*)&Pt[(2 * wv + r_) * 16 + l15][kb];
#pragma unroll
            for (int c = 0; c < 8; c++) {
                bf16x8 bb = *(const bf16x8*)(Gb + ((c * 16 + l15) << 7) + kb);
#pragma unroll
                for (int r_ = 0; r_ < 2; r_++)
                    acc[r_][c] = __builtin_amdgcn_mfma_f32_16x16x32_bf16(
                        af[r_], bb, acc[r_][c], 0, 0, 0);
            }
        }
#pragma unroll
        for (int r_ = 0; r_ < 2; r_++)
#pragma unroll
            for (int reg = 0; reg < 4; reg++) {
                int g = (2 * wv + r_) * 16 + quad * 4 + reg;
                float ps = 0.f;
#pragma unroll
                for (int c = 0; c < 8; c++)
                    ps += acc[r_][c][reg] * bf2f(P[c * 16 + l15][g]);
                ps += __shfl_xor(ps, 1); ps += __shfl_xor(ps, 2);
                ps += __shfl_xor(ps, 4); ps += __shfl_xor(ps, 8);
                if (l15 == 0) vacc[g] = ps;
            }
    }
    __syncthreads();
    if (tid < 128) {
        float m1 = w0v[tid] * (1.f / LL);
        float v1 = vacc[tid] * (1.f / LL) - m1 * m1;
        a1v[tid] = gamma[tid] * rsqrtf(v1 + EPSF);
        vacc[tid] = 0.f;
    }
    __syncthreads();
    {   // scale P columns by a1 (P2 = P' diag(a1))
        int f = tid & 127, gh = tid >> 7;
        for (int g2 = 0; g2 < 64; g2++) {
            int g = gh * 64 + g2;
            P[f][g] = bfr(bf2f(P[f][g]) * a1v[g]);
        }
    }
    __syncthreads();
    // ---- m2: Rt = M^T P2^T  (M = I + ffw^T)
    {
        f32x4 acc[2][8];
#pragma unroll
        for (int r_ = 0; r_ < 2; r_++)
#pragma unroll
            for (int c = 0; c < 8; c++) acc[r_][c] = (f32x4){0.f, 0.f, 0.f, 0.f};
#pragma unroll
        for (int kk = 0; kk < 4; kk++) {
            const int kb = kk * 32 + quad * 8;
            frag_t af[2];
#pragma unroll
            for (int r_ = 0; r_ < 2; r_++) {
                int g = (2 * wv + r_) * 16 + l15;
                float4 m0 = *(const float4*)&ffw[(size_t)g * FDIM + kb];
                float4 m1 = *(const float4*)&ffw[(size_t)g * FDIM + kb + 4];
                float mm[8] = {m0.x, m0.y, m0.z, m0.w, m1.x, m1.y, m1.z, m1.w};
#pragma unroll
                for (int j = 0; j < 8; j++)
                    af[r_].u[j] = bfr(mm[j] + ((kb + j) == g ? 1.f : 0.f));
            }
#pragma unroll
            for (int c = 0; c < 8; c++) {
                bf16x8 bb = *(const bf16x8*)&P[c * 16 + l15][kb];
#pragma unroll
                for (int r_ = 0; r_ < 2; r_++)
                    acc[r_][c] = __builtin_amdgcn_mfma_f32_16x16x32_bf16(
                        af[r_].v, bb, acc[r_][c], 0, 0, 0);
            }
        }
#pragma unroll
        for (int r_ = 0; r_ < 2; r_++)
#pragma unroll
            for (int c = 0; c < 8; c++)
#pragma unroll
                for (int reg = 0; reg < 4; reg++)
                    Rt[(2 * wv + r_) * 16 + quad * 4 + reg][c * 16 + l15] =
                        bfr(acc[r_][c][reg]);
    }
    __syncthreads();
    // ---- m3: T = G R ; diag(T^T R)... v2 diag -> vacc
    {
        f32x4 acc[2][8];
#pragma unroll
        for (int r_ = 0; r_ < 2; r_++)
#pragma unroll
            for (int c = 0; c < 8; c++) acc[r_][c] = (f32x4){0.f, 0.f, 0.f, 0.f};
#pragma unroll
        for (int kk = 0; kk < 4; kk++) {
            const int kb = kk * 32 + quad * 8;
            bf16x8 af[2];
#pragma unroll
            for (int r_ = 0; r_ < 2; r_++)
                af[r_] = *(const bf16x8*)(Gb + (((2 * wv + r_) * 16 + l15) << 7) + kb);
#pragma unroll
            for (int c = 0; c < 8; c++) {
                bf16x8 bb = *(const bf16x8*)&Rt[c * 16 + l15][kb];
#pragma unroll
                for (int r_ = 0; r_ < 2; r_++)
                    acc[r_][c] = __builtin_amdgcn_mfma_f32_16x16x32_bf16(
                        af[r_], bb, acc[r_][c], 0, 0, 0);
            }
        }
#pragma unroll
        for (int c = 0; c < 8; c++) {
            int g = c * 16 + l15;
            float ps = 0.f;
#pragma unroll
            for (int r_ = 0; r_ < 2; r_++)
#pragma unroll
                for (int reg = 0; reg < 4; reg++) {
                    int f2 = (2 * wv + r_) * 16 + quad * 4 + reg;
                    ps += acc[r_][c][reg] * bf2f(Rt[g][f2]);
                }
            ps += __shfl_xor(ps, 16); ps += __shfl_xor(ps, 32);
            if (quad == 0) atomicAdd(&vacc[g], ps);
        }
    }
    __syncthreads();
    if (tid < 128) {
        int g = tid;
        float w = 0.f;
        for (int f = 0; f < 128; f++) w += sxv[f] * bf2f(Rt[g][f]);
        float wL = w * (1.f / LL);
        float v2 = vacc[g] * (1.f / LL) - wL * wL;
        float a2 = gamma[g] * rsqrtf(v2 + EPSF);
        a2v[g] = a2;
        ws[OFF_DV + b * FDIM + g] = beta[g] - wL * a2;
    }
    __syncthreads();
    {   // Ct[g][f] = Rt[g][f] * a2[g]
        unsigned short* Ct = (unsigned short*)(ws + OFF_CT) + ((size_t)b << 14);
        int g = tid >> 1, h = tid & 1;
        float a2 = a2v[g];
#pragma unroll
        for (int i = 0; i < 16; i++) {
            int f = h * 64 + i * 4;
            ushort4 r4 = *(ushort4*)&Rt[g][f];
            ushort4 o;
            o.x = bfr(bf2f(r4.x) * a2); o.y = bfr(bf2f(r4.y) * a2);
            o.z = bfr(bf2f(r4.z) * a2); o.w = bfr(bf2f(r4.w) * a2);
            *(ushort4*)&Ct[(g << 7) + f] = o;
        }
    }
}

// ---------------------------------------------------------------- K4: out = X @ C + d  (LDS-free streaming)
// grid (32, 32), 256 thr, 4 blocks/CU. A-frags direct from global fp32 (128B-coalesced
// per 16-row group, each element read once); B-frags direct from L2-resident Ct.
__global__ __launch_bounds__(256, 4) void k4_out(const float* __restrict__ x,
                                                 const float* __restrict__ ws,
                                                 float* __restrict__ out) {
    const int b = blockIdx.y, r0 = blockIdx.x * 128;
    const int tid = threadIdx.x;
    const int wv = tid >> 6, l15 = tid & 15, quad = (tid >> 4) & 3;
    const float* Xg = x + ((size_t)b * LL + r0) * FDIM;
    const unsigned short* Ct = (const unsigned short*)(ws + OFF_CT) + ((size_t)b << 14);

    f32x4 acc[2][8];
#pragma unroll
    for (int r_ = 0; r_ < 2; r_++)
#pragma unroll
        for (int c = 0; c < 8; c++) acc[r_][c] = (f32x4){0.f, 0.f, 0.f, 0.f};

#pragma unroll
    for (int kk = 0; kk < 4; kk++) {
        const int kb = kk * 32 + quad * 8;
        frag_t af[2];
#pragma unroll
        for (int r_ = 0; r_ < 2; r_++) {
            int row = (2 * wv + r_) * 16 + l15;
            float4 v0 = *(const float4*)&Xg[(size_t)row * FDIM + kb];
            float4 v1 = *(const float4*)&Xg[(size_t)row * FDIM + kb + 4];
            af[r_].u[0] = bfr(v0.x); af[r_].u[1] = bfr(v0.y);
            af[r_].u[2] = bfr(v0.z); af[r_].u[3] = bfr(v0.w);
            af[r_].u[4] = bfr(v1.x); af[r_].u[5] = bfr(v1.y);
            af[r_].u[6] = bfr(v1.z); af[r_].u[7] = bfr(v1.w);
        }
#pragma unroll
        for (int c = 0; c < 8; c++) {
            bf16x8 bb = *(const bf16x8*)&Ct[((c * 16 + l15) << 7) + kb];
#pragma unroll
            for (int r_ = 0; r_ < 2; r_++)
                acc[r_][c] = __builtin_amdgcn_mfma_f32_16x16x32_bf16(
                    af[r_].v, bb, acc[r_][c], 0, 0, 0);
        }
    }
    float dreg[8];
#pragma unroll
    for (int c = 0; c < 8; c++) dreg[c] = ws[OFF_DV + b * FDIM + c * 16 + l15];
    float* Ob = out + ((size_t)b * LL + r0) * FDIM;
#pragma unroll
    for (int r_ = 0; r_ < 2; r_++)
#pragma unroll
        for (int c = 0; c < 8; c++)
#pragma unroll
            for (int reg = 0; reg < 4; reg++) {
                int row = (2 * wv + r_) * 16 + quad * 4 + reg;
                Ob[(size_t)row * FDIM + c * 16 + l15] = acc[r_][c][reg] + dreg[c];
            }
}

extern "C" void kernel_launch(void* const* d_in, const int* in_sizes, int n_in,
                              void* d_out, int out_size, void* d_ws, size_t ws_size,
                              hipStream_t stream) {
    const float* x     = (const float*)d_in[0];
    const float* q_w   = (const float*)d_in[1];
    const float* q_b   = (const float*)d_in[2];
    const float* k_w   = (const float*)d_in[3];
    const float* k_b   = (const float*)d_in[4];
    const float* ff_w  = (const float*)d_in[5];
    // ff_b cancels exactly under the final instance norm
    const float* gamma = (const float*)d_in[7];
    const float* beta  = (const float*)d_in[8];
    float* out = (float*)d_out;
    float* ws  = (float*)d_ws;

    hipMemsetAsync((char*)d_ws + (size_t)OFF_SX * 4, 0, (size_t)12288 * 4, stream);

    coeff_kernel<<<16, 256, 0, stream>>>(q_w, q_b, k_w, k_b, ws);
    k1_gram<<<dim3(NCH, 32), 256, 0, stream>>>(x, ws);
    kred<<<128, 256, 0, stream>>>(ws);
    k3_chain<<<32, 256, 0, stream>>>(ws, ff_w, gamma, beta);
    k4_out<<<dim3(32, 32), 256, 0, stream>>>(x, ws, out);
}

// Round 5
// 228.838 us; speedup vs baseline: 1.1296x; 1.1296x over previous
//
#include <hip/hip_runtime.h>
#include <math.h>

typedef __attribute__((ext_vector_type(8))) short bf16x8;
typedef __attribute__((ext_vector_type(4))) float f32x4;

#define BATCH 32
#define LL    4096
#define FDIM  128
#define NLEV  12
#define EPSF  1e-5f
#define RSQRTF 0.08838834764831845f
#define NCH   16

// ws layout (float offsets)
#define OFF_CQ 0          // 4096
#define OFF_CK 4096       // 4096
#define OFF_D  8192       // 2 (dq, dk)
#define OFF_SX 8320       // 32*128 (zeroed)
#define OFF_QS 12416      // 32*128 (zeroed)
#define OFF_KS 16512      // 32*128 (zeroed)
#define OFF_DV 20608      // 32*128
#define OFF_GP 24704      // 16*32*16384 fp32 partials = 8388608
#define OFF_GB 8413312    // G bf16: 32*16384 ushort = 262144 float slots
#define OFF_CT 8675456    // Ct bf16: 262144 float slots

typedef union { bf16x8 v; unsigned short u[8]; } frag_t;

__device__ inline unsigned short bfr(float f) {   // fp32 -> bf16 RTNE
    union { float f; unsigned u; } v; v.f = f;
    unsigned r = v.u + 0x7FFF + ((v.u >> 16) & 1);
    return (unsigned short)(r >> 16);
}
__device__ inline float bf2f(unsigned short h) {
    union { unsigned u; float f; } v; v.u = ((unsigned)h) << 16; return v.f;
}

// ---------------------------------------------------------------- coeff
__global__ void coeff_kernel(const float* __restrict__ qw, const float* __restrict__ qb,
                             const float* __restrict__ kw, const float* __restrict__ kb,
                             float* __restrict__ ws) {
    int l = blockIdx.x * 256 + threadIdx.x;
    float cq = 1.f, ck = 1.f;
#pragma unroll
    for (int i = 0; i < NLEV; i++) {
        int bit = (l >> i) & 1;
        cq *= qw[2 * i + bit];
        ck *= kw[2 * i + bit];
    }
    ws[OFF_CQ + l] = cq;
    ws[OFF_CK + l] = ck;
    if (l == 0) {
        float dq = 0.f, dk = 0.f;
        for (int i = 0; i < NLEV; i++) {
            dq = (qw[2 * i] + qw[2 * i + 1]) * dq + qb[i];
            dk = (kw[2 * i] + kw[2 * i + 1]) * dk + kb[i];
        }
        ws[OFF_D]     = dq;
        ws[OFF_D + 1] = dk;
    }
}

// ---------------------------------------------------------------- K1: G partials + fp32 sums
// grid (16, 32), 256 thr. 256 rows/chunk, 4 tiles of 64 rows.
// stage1: coalesced float4 -> natural LDS Xn; stage2: LDS transpose -> swizzled XsT (dbuf);
// compute: conflict-free b128 frags, MFMA (A and B share frags since G = X^T X).
__global__ __launch_bounds__(256) void k1_gram(const float* __restrict__ x,
                                               float* __restrict__ ws) {
    __shared__ __align__(16) unsigned short Xn[64][136];
    __shared__ __align__(16) unsigned short XsT[2][128][64];
    __shared__ float sa[128], qa[128], ka[128];
    const int b = blockIdx.y, ch = blockIdx.x;
    const int tid = threadIdx.x;
    const int wv = tid >> 6, l15 = tid & 15, quad = (tid >> 4) & 3;
    const float* Xb  = x + ((size_t)b * LL + ch * 256) * FDIM;
    const float* cqp = ws + OFF_CQ + ch * 256;
    const float* ckp = ws + OFF_CK + ch * 256;
    if (tid < 128) { sa[tid] = 0.f; qa[tid] = 0.f; ka[tid] = 0.f; }

    const int c4    = tid & 31;      // float4 col group: cols 4*c4 .. 4*c4+3
    const int rbase = tid >> 5;      // 0..7
    const int s2c   = tid & 127;     // stage2 column
    const int s2rh  = tid >> 7;      // 0..1

    float sxr[4] = {0,0,0,0}, qr[4] = {0,0,0,0}, kr[4] = {0,0,0,0};
    f32x4 acc[2][8];
#pragma unroll
    for (int r_ = 0; r_ < 2; r_++)
#pragma unroll
        for (int c = 0; c < 8; c++) acc[r_][c] = (f32x4){0.f, 0.f, 0.f, 0.f};

    auto stage1 = [&](int t) {
        const float* Xt = Xb + (size_t)t * 64 * FDIM;
#pragma unroll
        for (int p = 0; p < 8; p++) {
            int row = p * 8 + rbase;
            float4 v = *(const float4*)&Xt[(size_t)row * FDIM + c4 * 4];
            float cqv = cqp[t * 64 + row], ckv = ckp[t * 64 + row];
            sxr[0] += v.x; sxr[1] += v.y; sxr[2] += v.z; sxr[3] += v.w;
            qr[0] += cqv * v.x; qr[1] += cqv * v.y; qr[2] += cqv * v.z; qr[3] += cqv * v.w;
            kr[0] += ckv * v.x; kr[1] += ckv * v.y; kr[2] += ckv * v.z; kr[3] += ckv * v.w;
            ushort4 h; h.x = bfr(v.x); h.y = bfr(v.y); h.z = bfr(v.z); h.w = bfr(v.w);
            *(ushort4*)&Xn[row][c4 * 4] = h;
        }
    };
    auto stage2 = [&](int t) {
        int buf = t & 1;
#pragma unroll
        for (int g2 = 0; g2 < 4; g2++) {
            int g = s2rh * 4 + g2;               // l-group 0..7
            frag_t fr;
#pragma unroll
            for (int i = 0; i < 8; i++) fr.u[i] = Xn[g * 8 + i][s2c];
            *(bf16x8*)&XsT[buf][s2c][(g ^ (s2c & 7)) * 8] = fr.v;
        }
    };
    auto compute = [&](int t) {
        int buf = t & 1;
#pragma unroll
        for (int kk = 0; kk < 2; kk++) {
            bf16x8 fr[8];
#pragma unroll
            for (int t2 = 0; t2 < 8; t2++) {
                int f = t2 * 16 + l15;
                fr[t2] = *(const bf16x8*)&XsT[buf][f][((kk * 4 + quad) ^ (f & 7)) * 8];
            }
#pragma unroll
            for (int r_ = 0; r_ < 2; r_++)
#pragma unroll
                for (int c = 0; c < 8; c++)
                    acc[r_][c] = __builtin_amdgcn_mfma_f32_16x16x32_bf16(
                        fr[2 * wv + r_], fr[c], acc[r_][c], 0, 0, 0);
        }
    };

    stage1(0);
    __syncthreads();
    stage2(0);
    __syncthreads();
    for (int t = 0; t < 4; t++) {
        if (t < 3) stage1(t + 1);       // writes Xn (stage2(t) already consumed it)
        compute(t);                     // reads XsT[t&1]
        __syncthreads();
        if (t < 3) { stage2(t + 1); __syncthreads(); }
    }

    float* Gp = ws + OFF_GP + (((size_t)ch * 32 + b) << 14);
#pragma unroll
    for (int r_ = 0; r_ < 2; r_++)
#pragma unroll
        for (int c = 0; c < 8; c++)
#pragma unroll
            for (int reg = 0; reg < 4; reg++)
                Gp[(((2 * wv + r_) * 16 + quad * 4 + reg) << 7) + c * 16 + l15] =
                    acc[r_][c][reg];
#pragma unroll
    for (int j = 0; j < 4; j++) {
        int f = c4 * 4 + j;
        atomicAdd(&sa[f], sxr[j]);
        atomicAdd(&qa[f], qr[j]);
        atomicAdd(&ka[f], kr[j]);
    }
    __syncthreads();
    if (tid < 128) {
        atomicAdd(&ws[OFF_SX + b * FDIM + tid], sa[tid]);
        atomicAdd(&ws[OFF_QS + b * FDIM + tid], qa[tid]);
        atomicAdd(&ws[OFF_KS + b * FDIM + tid], ka[tid]);
    }
}

// ---------------------------------------------------------------- Kred: sum 16 partials -> G bf16
__global__ void kred(float* __restrict__ ws) {
    const int b = blockIdx.x >> 2, s = blockIdx.x & 3;
    const int tid = threadIdx.x;
    const int base = s << 12;
    float acc[16];
#pragma unroll
    for (int i = 0; i < 16; i++) acc[i] = 0.f;
    for (int ch = 0; ch < NCH; ch++) {
        const float* gp = ws + OFF_GP + (((size_t)ch * 32 + b) << 14) + base;
#pragma unroll
        for (int i = 0; i < 4; i++) {
            float4 v = *(const float4*)&gp[(tid + i * 256) * 4];
            acc[i * 4 + 0] += v.x; acc[i * 4 + 1] += v.y;
            acc[i * 4 + 2] += v.z; acc[i * 4 + 3] += v.w;
        }
    }
    unsigned short* gb = (unsigned short*)(ws + OFF_GB) + ((size_t)b << 14) + base;
#pragma unroll
    for (int i = 0; i < 4; i++) {
        ushort4 h;
        h.x = bfr(acc[i * 4 + 0]); h.y = bfr(acc[i * 4 + 1]);
        h.z = bfr(acc[i * 4 + 2]); h.w = bfr(acc[i * 4 + 3]);
        *(ushort4*)&gb[(tid + i * 256) * 4] = h;
    }
}

// ---------------------------------------------------------------- K3: per-batch 128^3 chain
__global__ __launch_bounds__(256) void k3_chain(float* __restrict__ ws,
                                                const float* __restrict__ ffw,
                                                const float* __restrict__ gamma,
                                                const float* __restrict__ beta) {
    __shared__ __align__(16) unsigned short P[128][136];
    __shared__ __align__(16) unsigned short Pt[128][136];
    __shared__ __align__(16) unsigned short Rt[128][136];
    __shared__ float qs[128], kvv[128], mv[128], invs[128], sxv[128],
                     a1v[128], a2v[128], w0v[128], vacc[128], kmm[2];
    const int b = blockIdx.x, tid = threadIdx.x;
    const int wv = tid >> 6, l15 = tid & 15, quad = (tid >> 4) & 3;
    const unsigned short* Gb = (const unsigned short*)(ws + OFF_GB) + ((size_t)b << 14);

    if (tid < 128) {
        sxv[tid] = ws[OFF_SX + b * FDIM + tid];
        qs[tid]  = (ws[OFF_QS + b * FDIM + tid] + ws[OFF_D]) * RSQRTF;
        kvv[tid] = ws[OFF_KS + b * FDIM + tid] + ws[OFF_D + 1];
        vacc[tid] = 0.f;
    }
    __syncthreads();
    if (tid < 64) {
        float a = kvv[tid], c = kvv[tid + 64];
        float mx = fmaxf(a, c), mn = fminf(a, c);
        for (int o = 32; o; o >>= 1) {
            mx = fmaxf(mx, __shfl_xor(mx, o));
            mn = fminf(mn, __shfl_xor(mn, o));
        }
        if (tid == 0) { kmm[0] = mn; kmm[1] = mx; }
    }
    __syncthreads();
    if (tid < 128) {
        float qf = qs[tid];
        float m  = fmaxf(qf * kmm[0], qf * kmm[1]);
        float s  = 0.f;
        for (int g = 0; g < 128; g++) s += __expf(qf * kvv[g] - m);
        mv[tid] = m; invs[tid] = 1.f / s;
    }
    __syncthreads();
    {   // P-gen: P'[f][g] = softmax + I
        int f = tid & 127, gh = tid >> 7;
        float qf = qs[f], iv = invs[f], m = mv[f];
        for (int g2 = 0; g2 < 64; g2++) {
            int g = gh * 64 + g2;
            float e = __expf(qf * kvv[g] - m) * iv + (f == g ? 1.f : 0.f);
            unsigned short h = bfr(e);
            P[f][g] = h; Pt[g][f] = h;
        }
    }
    __syncthreads();
    if (tid < 128) {                   // w0 = sX @ P'
        float w = 0.f;
        for (int f = 0; f < 128; f++) w += sxv[f] * bf2f(Pt[tid][f]);
        w0v[tid] = w;
    }
    __syncthreads();
    // ---- m1: T0t = P'^T G ; diag(T0 P') -> vacc
    {
        f32x4 acc[2][8];
#pragma unroll
        for (int r_ = 0; r_ < 2; r_++)
#pragma unroll
            for (int c = 0; c < 8; c++) acc[r_][c] = (f32x4){0.f, 0.f, 0.f, 0.f};
#pragma unroll
        for (int kk = 0; kk < 4; kk++) {
            const int kb = kk * 32 + quad * 8;
            bf16x8 af[2];
#pragma unroll
            for (int r_ = 0; r_ < 2; r_++)
                af[r_] = *(const bf16x8*)&Pt[(2 * wv + r_) * 16 + l15][kb];
#pragma unroll
            for (int c = 0; c < 8; c++) {
                bf16x8 bb = *(const bf16x8*)(Gb + ((c * 16 + l15) << 7) + kb);
#pragma unroll
                for (int r_ = 0; r_ < 2; r_++)
                    acc[r_][c] = __builtin_amdgcn_mfma_f32_16x16x32_bf16(
                        af[r_], bb, acc[r_][c], 0, 0, 0);
            }
        }
#pragma unroll
        for (int r_ = 0; r_ < 2; r_++)
#pragma unroll
            for (int reg = 0; reg < 4; reg++) {
                int g = (2 * wv + r_) * 16 + quad * 4 + reg;
                float ps = 0.f;
#pragma unroll
                for (int c = 0; c < 8; c++)
                    ps += acc[r_][c][reg] * bf2f(P[c * 16 + l15][g]);
                ps += __shfl_xor(ps, 1); ps += __shfl_xor(ps, 2);
                ps += __shfl_xor(ps, 4); ps += __shfl_xor(ps, 8);
                if (l15 == 0) vacc[g] = ps;
            }
    }
    __syncthreads();
    if (tid < 128) {
        float m1 = w0v[tid] * (1.f / LL);
        float v1 = vacc[tid] * (1.f / LL) - m1 * m1;
        a1v[tid] = gamma[tid] * rsqrtf(v1 + EPSF);
        vacc[tid] = 0.f;
    }
    __syncthreads();
    {   // P2 = P' diag(a1)
        int f = tid & 127, gh = tid >> 7;
        for (int g2 = 0; g2 < 64; g2++) {
            int g = gh * 64 + g2;
            P[f][g] = bfr(bf2f(P[f][g]) * a1v[g]);
        }
    }
    __syncthreads();
    // ---- m2: Rt = M^T P2^T  (M = I + ffw^T)
    {
        f32x4 acc[2][8];
#pragma unroll
        for (int r_ = 0; r_ < 2; r_++)
#pragma unroll
            for (int c = 0; c < 8; c++) acc[r_][c] = (f32x4){0.f, 0.f, 0.f, 0.f};
#pragma unroll
        for (int kk = 0; kk < 4; kk++) {
            const int kb = kk * 32 + quad * 8;
            frag_t af[2];
#pragma unroll
            for (int r_ = 0; r_ < 2; r_++) {
                int g = (2 * wv + r_) * 16 + l15;
                float4 m0 = *(const float4*)&ffw[(size_t)g * FDIM + kb];
                float4 m1 = *(const float4*)&ffw[(size_t)g * FDIM + kb + 4];
                float mm[8] = {m0.x, m0.y, m0.z, m0.w, m1.x, m1.y, m1.z, m1.w};
#pragma unroll
                for (int j = 0; j < 8; j++)
                    af[r_].u[j] = bfr(mm[j] + ((kb + j) == g ? 1.f : 0.f));
            }
#pragma unroll
            for (int c = 0; c < 8; c++) {
                bf16x8 bb = *(const bf16x8*)&P[c * 16 + l15][kb];
#pragma unroll
                for (int r_ = 0; r_ < 2; r_++)
                    acc[r_][c] = __builtin_amdgcn_mfma_f32_16x16x32_bf16(
                        af[r_].v, bb, acc[r_][c], 0, 0, 0);
            }
        }
#pragma unroll
        for (int r_ = 0; r_ < 2; r_++)
#pragma unroll
            for (int c = 0; c < 8; c++)
#pragma unroll
                for (int reg = 0; reg < 4; reg++)
                    Rt[(2 * wv + r_) * 16 + quad * 4 + reg][c * 16 + l15] =
                        bfr(acc[r_][c][reg]);
    }
    __syncthreads();
    // ---- m3: T = G R ; v2 diag -> vacc
    {
        f32x4 acc[2][8];
#pragma unroll
        for (int r_ = 0; r_ < 2; r_++)
#pragma unroll
            for (int c = 0; c < 8; c++) acc[r_][c] = (f32x4){0.f, 0.f, 0.f, 0.f};
#pragma unroll
        for (int kk = 0; kk < 4; kk++) {
            const int kb = kk * 32 + quad * 8;
            bf16x8 af[2];
#pragma unroll
            for (int r_ = 0; r_ < 2; r_++)
                af[r_] = *(const bf16x8*)(Gb + (((2 * wv + r_) * 16 + l15) << 7) + kb);
#pragma unroll
            for (int c = 0; c < 8; c++) {
                bf16x8 bb = *(const bf16x8*)&Rt[c * 16 + l15][kb];
#pragma unroll
                for (int r_ = 0; r_ < 2; r_++)
                    acc[r_][c] = __builtin_amdgcn_mfma_f32_16x16x32_bf16(
                        af[r_], bb, acc[r_][c], 0, 0, 0);
            }
        }
#pragma unroll
        for (int c = 0; c < 8; c++) {
            int g = c * 16 + l15;
            float ps = 0.f;
#pragma unroll
            for (int r_ = 0; r_ < 2; r_++)
#pragma unroll
                for (int reg = 0; reg < 4; reg++) {
                    int f2 = (2 * wv + r_) * 16 + quad * 4 + reg;
                    ps += acc[r_][c][reg] * bf2f(Rt[g][f2]);
                }
            ps += __shfl_xor(ps, 16); ps += __shfl_xor(ps, 32);
            if (quad == 0) atomicAdd(&vacc[g], ps);
        }
    }
    __syncthreads();
    if (tid < 128) {
        int g = tid;
        float w = 0.f;
        for (int f = 0; f < 128; f++) w += sxv[f] * bf2f(Rt[g][f]);
        float wL = w * (1.f / LL);
        float v2 = vacc[g] * (1.f / LL) - wL * wL;
        float a2 = gamma[g] * rsqrtf(v2 + EPSF);
        a2v[g] = a2;
        ws[OFF_DV + b * FDIM + g] = beta[g] - wL * a2;
    }
    __syncthreads();
    {   // Ct[g][f] = Rt[g][f] * a2[g]
        unsigned short* Ct = (unsigned short*)(ws + OFF_CT) + ((size_t)b << 14);
        int g = tid >> 1, h = tid & 1;
        float a2 = a2v[g];
#pragma unroll
        for (int i = 0; i < 16; i++) {
            int f = h * 64 + i * 4;
            ushort4 r4 = *(ushort4*)&Rt[g][f];
            ushort4 o;
            o.x = bfr(bf2f(r4.x) * a2); o.y = bfr(bf2f(r4.y) * a2);
            o.z = bfr(bf2f(r4.z) * a2); o.w = bfr(bf2f(r4.w) * a2);
            *(ushort4*)&Ct[(g << 7) + f] = o;
        }
    }
}

// ---------------------------------------------------------------- K4: out = X @ C + d
// grid (64, 32), 256 thr. A-frags natural b128 from LDS (no transpose needed);
// B-frags direct from L2-resident Ct (16 rows x 64B dense per instruction).
__global__ __launch_bounds__(256) void k4_out(const float* __restrict__ x,
                                              const float* __restrict__ ws,
                                              float* __restrict__ out) {
    __shared__ __align__(16) unsigned short Xs[64][136];
    const int b = blockIdx.y, r0 = blockIdx.x * 64;
    const int tid = threadIdx.x;
    const int wv = tid >> 6, l15 = tid & 15, quad = (tid >> 4) & 3;
    const float* Xg = x + ((size_t)b * LL + r0) * FDIM;
    const unsigned short* Ct = (const unsigned short*)(ws + OFF_CT) + ((size_t)b << 14);

#pragma unroll
    for (int p = 0; p < 8; p++) {
        int idx = p * 256 + tid;
        int row = idx >> 5, c4 = idx & 31;
        float4 v = *(const float4*)&Xg[(size_t)row * FDIM + c4 * 4];
        ushort4 h; h.x = bfr(v.x); h.y = bfr(v.y); h.z = bfr(v.z); h.w = bfr(v.w);
        *(ushort4*)&Xs[row][c4 * 4] = h;
    }
    float dreg[8];
#pragma unroll
    for (int c = 0; c < 8; c++) dreg[c] = ws[OFF_DV + b * FDIM + c * 16 + l15];
    __syncthreads();

    const int rowA = wv * 16 + l15;
    f32x4 acc[8];
#pragma unroll
    for (int c = 0; c < 8; c++) acc[c] = (f32x4){0.f, 0.f, 0.f, 0.f};
#pragma unroll
    for (int kk = 0; kk < 4; kk++) {
        const int kb = kk * 32 + quad * 8;
        bf16x8 a = *(const bf16x8*)&Xs[rowA][kb];
#pragma unroll
        for (int c = 0; c < 8; c++) {
            bf16x8 bb = *(const bf16x8*)&Ct[((c * 16 + l15) << 7) + kb];
            acc[c] = __builtin_amdgcn_mfma_f32_16x16x32_bf16(a, bb, acc[c], 0, 0, 0);
        }
    }
    float* Ob = out + ((size_t)b * LL + r0) * FDIM;
#pragma unroll
    for (int c = 0; c < 8; c++)
#pragma unroll
        for (int reg = 0; reg < 4; reg++) {
            int row = wv * 16 + quad * 4 + reg;
            Ob[(size_t)row * FDIM + c * 16 + l15] = acc[c][reg] + dreg[c];
        }
}

extern "C" void kernel_launch(void* const* d_in, const int* in_sizes, int n_in,
                              void* d_out, int out_size, void* d_ws, size_t ws_size,
                              hipStream_t stream) {
    const float* x     = (const float*)d_in[0];
    const float* q_w   = (const float*)d_in[1];
    const float* q_b   = (const float*)d_in[2];
    const float* k_w   = (const float*)d_in[3];
    const float* k_b   = (const float*)d_in[4];
    const float* ff_w  = (const float*)d_in[5];
    // ff_b cancels exactly under the final instance norm
    const float* gamma = (const float*)d_in[7];
    const float* beta  = (const float*)d_in[8];
    float* out = (float*)d_out;
    float* ws  = (float*)d_ws;

    hipMemsetAsync((char*)d_ws + (size_t)OFF_SX * 4, 0, (size_t)12288 * 4, stream);

    coeff_kernel<<<16, 256, 0, stream>>>(q_w, q_b, k_w, k_b, ws);
    k1_gram<<<dim3(NCH, 32), 256, 0, stream>>>(x, ws);
    kred<<<128, 256, 0, stream>>>(ws);
    k3_chain<<<32, 256, 0, stream>>>(ws, ff_w, gamma, beta);
    k4_out<<<dim3(64, 32), 256, 0, stream>>>(x, ws, out);
}